// Round 6
// baseline (276.618 us; speedup 1.0000x reference)
//
#include <hip/hip_runtime.h>
#include <stdint.h>

#define D_MODEL 1024
#define SEQ 2048
#define HALF 1024
#define K_EIG 24
#define WE_ROWS 1120   // 1024 + 96 zero pad (w prefetch overrun)
#define GUARD 128      // zero rows before EACH slice (lowest staged row = -128)
#define HALF_P (HALF + GUARD)   // padded slice stride (rows)

typedef __attribute__((ext_vector_type(8))) short bf16x8;
typedef __attribute__((ext_vector_type(4))) float f32x4;

#define GAS __attribute__((address_space(1)))
#define LAS __attribute__((address_space(3)))

static __device__ __forceinline__ unsigned short f2bf(float f) {
  union { float f; uint32_t u; } v; v.f = f;
  uint32_t u = v.u;
  u += 0x7FFFu + ((u >> 16) & 1u);
  return (unsigned short)(u >> 16);
}

// ---------------- x (fp32) -> bf16 ----------------
__global__ void k_convert_x(const float* __restrict__ x, unsigned short* __restrict__ xb, int n4) {
  int idx = blockIdx.x * blockDim.x + threadIdx.x;
  if (idx < n4) {
    float4 v = ((const float4*)x)[idx];
    ushort4 o;
    o.x = f2bf(v.x); o.y = f2bf(v.y); o.z = f2bf(v.z); o.w = f2bf(v.w);
    ((ushort4*)xb)[idx] = o;
  }
}

// ---------------- zero the per-slice guard rows of u (bf16) ----------------
__global__ void k_zero_guard(float* __restrict__ u) {
  // 8 slices x GUARD(128) rows x 2048B = 16384 float4 per slice
  int idx = blockIdx.x * blockDim.x + threadIdx.x;   // grid 512x256 = 131072
  int r = idx >> 14;
  int off = idx & 16383;
  ((float4*)u)[(size_t)r * (HALF_P * 128) + off] = make_float4(0.f, 0.f, 0.f, 0.f);
}

// ------------- M_inputs [K][N] fp32 -> Mt [N][K] bf16 -------------
__global__ void k_transpose_M(const float* __restrict__ M, unsigned short* __restrict__ Mt) {
  __shared__ float tile[32][33];
  int k0 = blockIdx.y * 32, n0 = blockIdx.x * 32;
  int tx = threadIdx.x & 31, ty = threadIdx.x >> 5;
  #pragma unroll
  for (int r = 0; r < 32; r += 8)
    tile[ty + r][tx] = M[(size_t)(k0 + ty + r) * D_MODEL + n0 + tx];
  __syncthreads();
  #pragma unroll
  for (int r = 0; r < 32; r += 8)
    Mt[(size_t)(n0 + ty + r) * D_MODEL + k0 + tx] = f2bf(tile[tx][ty + r]);
}

// ------------- w_e[j][d] = 2 * sum_k phi[2j][k] * Mf[k][d]; rows >= HALF are zero -------------
__global__ void k_we(const float* __restrict__ phi, const float* __restrict__ Mf,
                     float* __restrict__ we) {
  int j = blockIdx.x;
  if (j >= HALF) {
    for (int d = threadIdx.x; d < D_MODEL; d += blockDim.x)
      we[(size_t)j * D_MODEL + d] = 0.f;
    return;
  }
  __shared__ float ph[K_EIG];
  if (threadIdx.x < K_EIG) ph[threadIdx.x] = phi[(size_t)(2 * j) * K_EIG + threadIdx.x];
  __syncthreads();
  for (int d = threadIdx.x; d < D_MODEL; d += blockDim.x) {
    float s = 0.f;
    #pragma unroll
    for (int k = 0; k < K_EIG; ++k) s = fmaf(ph[k], Mf[(size_t)k * D_MODEL + d], s);
    we[(size_t)j * D_MODEL + d] = 2.0f * s;
  }
}

// ------------- u = x @ M (bf16 MFMA, B^T input), epilogue writes padded bf16 u_h[r][GUARD+i][d] -------------
__global__ __launch_bounds__(256) void k_gemm(const unsigned short* __restrict__ A,
                                              const unsigned short* __restrict__ Bt,
                                              unsigned short* __restrict__ U) {
  __shared__ unsigned short As[128 * 32];
  __shared__ unsigned short Bs[128 * 32];
  const int m0 = (int)blockIdx.x * 128;
  const int n0 = (int)blockIdx.y * 128;
  const int tid = threadIdx.x;
  const int lane = tid & 63;
  const int wave = tid >> 6;
  const int wm = wave >> 1, wn = wave & 1;
  const int srow = lane >> 2;
  const int skoff = (lane & 3) * 8;

  f32x4 acc[4][4] = {};

  for (int k0 = 0; k0 < 1024; k0 += 32) {
    __syncthreads();
    #pragma unroll
    for (int c = 0; c < 2; ++c) {
      int rbase = wave * 32 + c * 16;
      const unsigned short* src = A + (size_t)(m0 + rbase + srow) * 1024 + k0 + skoff;
      __builtin_amdgcn_global_load_lds((const GAS void*)src, (LAS void*)(As + rbase * 32), 16, 0, 0);
    }
    #pragma unroll
    for (int c = 0; c < 2; ++c) {
      int rbase = wave * 32 + c * 16;
      const unsigned short* src = Bt + (size_t)(n0 + rbase + srow) * 1024 + k0 + skoff;
      __builtin_amdgcn_global_load_lds((const GAS void*)src, (LAS void*)(Bs + rbase * 32), 16, 0, 0);
    }
    __syncthreads();

    bf16x8 a[4], b[4];
    #pragma unroll
    for (int mt = 0; mt < 4; ++mt)
      a[mt] = *(const bf16x8*)(As + ((wm * 64 + mt * 16 + (lane & 15)) * 32 + (lane >> 4) * 8));
    #pragma unroll
    for (int nt = 0; nt < 4; ++nt)
      b[nt] = *(const bf16x8*)(Bs + ((wn * 64 + nt * 16 + (lane & 15)) * 32 + (lane >> 4) * 8));
    #pragma unroll
    for (int mt = 0; mt < 4; ++mt)
      #pragma unroll
      for (int nt = 0; nt < 4; ++nt)
        acc[mt][nt] = __builtin_amdgcn_mfma_f32_16x16x32_bf16(a[mt], b[nt], acc[mt][nt], 0, 0, 0);
  }

  const int crow = (lane >> 4) * 4;
  const int ccol = lane & 15;
  #pragma unroll
  for (int mt = 0; mt < 4; ++mt) {
    #pragma unroll
    for (int q = 0; q < 4; ++q) {
      int m = m0 + wm * 64 + mt * 16 + crow + q;
      int b_ = m >> 11;
      int t = m & 2047;
      int r = (b_ << 1) | (t & 1);
      int i = t >> 1;
      unsigned short* dst = U + ((size_t)r * HALF_P + GUARD + i) * D_MODEL;
      #pragma unroll
      for (int nt = 0; nt < 4; ++nt)
        dst[n0 + wn * 64 + nt * 16 + ccol] = f2bf(acc[mt][nt][q]);
    }
  }
}

// ------------- depthwise causal conv: bf16 u in 32KB circular LDS, 8 outputs/thread -------------
// 512 thr = 64 d-lanes x 8 waves. i-tile 64, pairs (a,15-a): 17 chunks/block, 1024 blocks = 4/CU.
__device__ __forceinline__ void tap8(const float (&cu)[8], const float (&cw)[8],
                                     float (&win)[8], float (&acc)[8]) {
#pragma unroll
  for (int t = 0; t < 8; ++t) {
    float wv = cw[t];
#pragma unroll
    for (int o = 0; o < 8; ++o)
      acc[o] = fmaf(wv, win[(o - t) & 7], acc[o]);
    win[7 - t] = cu[t];
  }
}

__global__ __launch_bounds__(512, 8) void k_conv(const unsigned short* __restrict__ u,
                                                 const float* __restrict__ we,
                                                 float* __restrict__ out) {
  __shared__ unsigned short u_s[256 * 64];   // 32KB circular row buffer (slot = row & 255)
  const int flat = blockIdx.x;               // 0..1023
  const int dt = flat & 15;                  // d-column pinned per XCD (flat&7)
  const int r  = (flat >> 4) & 7;
  const int pp = flat >> 7;                  // 0..7
  const int d0 = dt * 64;
  const int tid = threadIdx.x;
  const int dl = tid & 63;
  const int ig = tid >> 6;                   // wave 0..7

  const unsigned short* ubase = u + ((size_t)r * HALF_P + GUARD) * D_MODEL + d0;
  const float* wb = we + d0 + dl;
  const int b_ = r >> 1, p = r & 1;

  // Stage 64 bf16 rows [lo, lo+64): each wave 8 rows, lane lane/8 -> row, 16B per lane.
  // LDS dest is wave-uniform base + lane*16 (8 rows = 1024B contiguous, wrap-safe: lo % 8 == 0).
#define STAGE64(lo)                                                                     \
  {                                                                                     \
    int row0 = (lo) + ig * 8;                                                           \
    const unsigned short* src = ubase + (size_t)(row0 + (dl >> 3)) * D_MODEL + (dl & 7) * 8; \
    __builtin_amdgcn_global_load_lds((const GAS void*)src,                              \
                                     (LAS void*)(u_s + (row0 & 255) * 64), 16, 0, 0);   \
  }

#define LDSU(buf)                                                                       \
  {                                                                                     \
    _Pragma("unroll") for (int t = 0; t < 8; ++t) {                                     \
      unsigned int hv = u_s[((urow - t) & 255) * 64 + dl];                              \
      buf[t] = __uint_as_float(hv << 16);                                               \
    }                                                                                   \
    urow -= 8;                                                                          \
  }

#define PW(buf)                                                                         \
  {                                                                                     \
    _Pragma("unroll") for (int t = 0; t < 8; ++t)                                       \
      buf[t] = wb[(size_t)(wrow + t) * D_MODEL];                                        \
    wrow += 8;                                                                          \
  }

#pragma unroll 1
  for (int tt = 0; tt < 2; ++tt) {
    const int a = tt ? pp : (15 - pp);   // heavy tile first; 17 chunks total per block
    const int i0 = a * 64;
    const int ibase = i0 + ig * 8;
    const int niter = a + 1;             // 64-tap chunks

    STAGE64(i0 - 64);
    STAGE64(i0);
    __syncthreads();

    float acc[8], win[8];
#pragma unroll
    for (int o = 0; o < 8; ++o) {
      acc[o] = 0.f;
      unsigned int hv = u_s[((ibase + o) & 255) * 64 + dl];
      win[o] = __uint_as_float(hv << 16);
    }

    float bu0[8], bu1[8], bw0[8], bw1[8];
    int urow = ibase - 1, wrow = 0;
    PW(bw0);

#pragma unroll 1
    for (int c = 0; c < niter; ++c) {
      STAGE64(i0 - 64 * c - 128);        // rows for chunk c+1, overlapped with compute
      LDSU(bu0);
      PW(bw1); LDSU(bu1); tap8(bu0, bw0, win, acc);
      PW(bw0); LDSU(bu0); tap8(bu1, bw1, win, acc);
      PW(bw1); LDSU(bu1); tap8(bu0, bw0, win, acc);
      PW(bw0); LDSU(bu0); tap8(bu1, bw1, win, acc);
      PW(bw1); LDSU(bu1); tap8(bu0, bw0, win, acc);
      PW(bw0); LDSU(bu0); tap8(bu1, bw1, win, acc);
      PW(bw1); LDSU(bu1); tap8(bu0, bw0, win, acc);
      PW(bw0);            tap8(bu1, bw1, win, acc);
      __syncthreads();
    }

#pragma unroll
    for (int o = 0; o < 8; ++o)
      out[((size_t)b_ * SEQ + 2 * (ibase + o) + p) * D_MODEL + d0 + dl] = acc[o];
  }
#undef STAGE64
#undef LDSU
#undef PW
}

extern "C" void kernel_launch(void* const* d_in, const int* in_sizes, int n_in,
                              void* d_out, int out_size, void* d_ws, size_t ws_size,
                              hipStream_t stream) {
  const float* x   = (const float*)d_in[0];   // [4][2048][1024]
  const float* Mi  = (const float*)d_in[1];   // [1024][1024]
  const float* Mf  = (const float*)d_in[2];   // [24][1024]
  const float* phi = (const float*)d_in[3];   // [2048][24]
  float* out = (float*)d_out;

  // x_bf (16MB) and Mt (2MB) live in d_out -- dead before conv writes out.
  unsigned short* x_bf = (unsigned short*)d_out;
  unsigned short* Mt   = (unsigned short*)((char*)d_out + (16u << 20));

  char* ws = (char*)d_ws;
  float* we          = (float*)(ws);                 // 1120*4KB = 4.59 MB
  unsigned short* u  = (unsigned short*)(ws + (5u << 20));   // 8*1152*1024*2 = 18.9 MB

  hipLaunchKernelGGL(k_zero_guard, dim3(512), dim3(256), 0, stream, (float*)u);
  hipLaunchKernelGGL(k_convert_x, dim3(8192), dim3(256), 0, stream, x, x_bf, 2097152);
  hipLaunchKernelGGL(k_transpose_M, dim3(32, 32), dim3(256), 0, stream, Mi, Mt);
  hipLaunchKernelGGL(k_we, dim3(WE_ROWS), dim3(256), 0, stream, phi, Mf, we);
  hipLaunchKernelGGL(k_gemm, dim3(64, 8), dim3(256), 0, stream, x_bf, Mt, u);
  hipLaunchKernelGGL(k_conv, dim3(1024), dim3(512), 0, stream, u, we, out);
}

// Round 7
// 185.400 us; speedup vs baseline: 1.4920x; 1.4920x over previous
//
#include <hip/hip_runtime.h>
#include <stdint.h>

#define D_MODEL 1024
#define SEQ 2048
#define HALF 1024
#define K_EIG 24
#define WE_ROWS 1120   // 1024 + 96 zero pad (w staging overrun: chunk 16 -> rows [1024,1088))
#define GUARD 192      // zero rows before EACH slice (lowest staged row = -192)
#define HALF_P (HALF + GUARD)   // padded slice stride (rows)

typedef __attribute__((ext_vector_type(8))) short bf16x8;
typedef __attribute__((ext_vector_type(4))) float f32x4;

#define GAS __attribute__((address_space(1)))
#define LAS __attribute__((address_space(3)))

static __device__ __forceinline__ unsigned short f2bf(float f) {
  union { float f; uint32_t u; } v; v.f = f;
  uint32_t u = v.u;
  u += 0x7FFFu + ((u >> 16) & 1u);
  return (unsigned short)(u >> 16);
}

// ---------------- x (fp32) -> bf16 ----------------
__global__ void k_convert_x(const float* __restrict__ x, unsigned short* __restrict__ xb, int n4) {
  int idx = blockIdx.x * blockDim.x + threadIdx.x;
  if (idx < n4) {
    float4 v = ((const float4*)x)[idx];
    ushort4 o;
    o.x = f2bf(v.x); o.y = f2bf(v.y); o.z = f2bf(v.z); o.w = f2bf(v.w);
    ((ushort4*)xb)[idx] = o;
  }
}

// ---------------- zero the per-slice guard rows of u (bf16) ----------------
__global__ void k_zero_guard(float4* __restrict__ u) {
  // per slice: GUARD(192) rows x 1024 bf16 x 2B / 16B = 24576 float4; grid (96, 8) x 256
  int off = blockIdx.x * 256 + threadIdx.x;
  int r = blockIdx.y;
  u[(size_t)r * (HALF_P * 128) + off] = make_float4(0.f, 0.f, 0.f, 0.f);
}

// ------------- M_inputs [K][N] fp32 -> Mt [N][K] bf16 -------------
__global__ void k_transpose_M(const float* __restrict__ M, unsigned short* __restrict__ Mt) {
  __shared__ float tile[32][33];
  int k0 = blockIdx.y * 32, n0 = blockIdx.x * 32;
  int tx = threadIdx.x & 31, ty = threadIdx.x >> 5;
  #pragma unroll
  for (int r = 0; r < 32; r += 8)
    tile[ty + r][tx] = M[(size_t)(k0 + ty + r) * D_MODEL + n0 + tx];
  __syncthreads();
  #pragma unroll
  for (int r = 0; r < 32; r += 8)
    Mt[(size_t)(n0 + ty + r) * D_MODEL + k0 + tx] = f2bf(tile[tx][ty + r]);
}

// ------------- w_e[j][d] = 2 * sum_k phi[2j][k] * Mf[k][d]; rows >= HALF are zero -------------
__global__ void k_we(const float* __restrict__ phi, const float* __restrict__ Mf,
                     float* __restrict__ we) {
  int j = blockIdx.x;
  if (j >= HALF) {
    for (int d = threadIdx.x; d < D_MODEL; d += blockDim.x)
      we[(size_t)j * D_MODEL + d] = 0.f;
    return;
  }
  __shared__ float ph[K_EIG];
  if (threadIdx.x < K_EIG) ph[threadIdx.x] = phi[(size_t)(2 * j) * K_EIG + threadIdx.x];
  __syncthreads();
  for (int d = threadIdx.x; d < D_MODEL; d += blockDim.x) {
    float s = 0.f;
    #pragma unroll
    for (int k = 0; k < K_EIG; ++k) s = fmaf(ph[k], Mf[(size_t)k * D_MODEL + d], s);
    we[(size_t)j * D_MODEL + d] = 2.0f * s;
  }
}

// ------------- u = x @ M (bf16 MFMA, B^T input), epilogue writes padded bf16 u_h[r][GUARD+i][d] -------------
__global__ __launch_bounds__(256) void k_gemm(const unsigned short* __restrict__ A,
                                              const unsigned short* __restrict__ Bt,
                                              unsigned short* __restrict__ U) {
  __shared__ unsigned short As[128 * 32];
  __shared__ unsigned short Bs[128 * 32];
  const int m0 = (int)blockIdx.x * 128;
  const int n0 = (int)blockIdx.y * 128;
  const int tid = threadIdx.x;
  const int lane = tid & 63;
  const int wave = tid >> 6;
  const int wm = wave >> 1, wn = wave & 1;
  const int srow = lane >> 2;
  const int skoff = (lane & 3) * 8;

  f32x4 acc[4][4] = {};

  for (int k0 = 0; k0 < 1024; k0 += 32) {
    __syncthreads();
    #pragma unroll
    for (int c = 0; c < 2; ++c) {
      int rbase = wave * 32 + c * 16;
      const unsigned short* src = A + (size_t)(m0 + rbase + srow) * 1024 + k0 + skoff;
      __builtin_amdgcn_global_load_lds((const GAS void*)src, (LAS void*)(As + rbase * 32), 16, 0, 0);
    }
    #pragma unroll
    for (int c = 0; c < 2; ++c) {
      int rbase = wave * 32 + c * 16;
      const unsigned short* src = Bt + (size_t)(n0 + rbase + srow) * 1024 + k0 + skoff;
      __builtin_amdgcn_global_load_lds((const GAS void*)src, (LAS void*)(Bs + rbase * 32), 16, 0, 0);
    }
    __syncthreads();

    bf16x8 a[4], b[4];
    #pragma unroll
    for (int mt = 0; mt < 4; ++mt)
      a[mt] = *(const bf16x8*)(As + ((wm * 64 + mt * 16 + (lane & 15)) * 32 + (lane >> 4) * 8));
    #pragma unroll
    for (int nt = 0; nt < 4; ++nt)
      b[nt] = *(const bf16x8*)(Bs + ((wn * 64 + nt * 16 + (lane & 15)) * 32 + (lane >> 4) * 8));
    #pragma unroll
    for (int mt = 0; mt < 4; ++mt)
      #pragma unroll
      for (int nt = 0; nt < 4; ++nt)
        acc[mt][nt] = __builtin_amdgcn_mfma_f32_16x16x32_bf16(a[mt], b[nt], acc[mt][nt], 0, 0, 0);
  }

  const int crow = (lane >> 4) * 4;
  const int ccol = lane & 15;
  #pragma unroll
  for (int mt = 0; mt < 4; ++mt) {
    #pragma unroll
    for (int q = 0; q < 4; ++q) {
      int m = m0 + wm * 64 + mt * 16 + crow + q;
      int b_ = m >> 11;
      int t = m & 2047;
      int r = (b_ << 1) | (t & 1);
      int i = t >> 1;
      unsigned short* dst = U + ((size_t)r * HALF_P + GUARD + i) * D_MODEL;
      #pragma unroll
      for (int nt = 0; nt < 4; ++nt)
        dst[n0 + wn * 64 + nt * 16 + ccol] = f2bf(acc[mt][nt][q]);
    }
  }
}

// ------------- depthwise causal conv: bf16 u (32KB) + fp32 w (2x16KB) both in LDS -------------
// 512 thr = 64 d-lanes x 8 waves, 16 outputs/thread. i-tile 128, pairs (a,7-a): 18 chunks/block.
template <int PH>
__device__ __forceinline__ void tap_group(const float (&cu)[8], const float (&cw)[8],
                                          float (&win)[16], float (&acc)[16]) {
#pragma unroll
  for (int t = 0; t < 8; ++t) {
    const int kf = (PH + t) & 15;
    float wv = cw[t];
#pragma unroll
    for (int o = 0; o < 16; ++o)
      acc[o] = fmaf(wv, win[(o - kf) & 15], acc[o]);
    win[(15 - kf) & 15] = cu[t];
  }
}

__global__ __launch_bounds__(512, 4) void k_conv(const unsigned short* __restrict__ u,
                                                 const float* __restrict__ we,
                                                 float* __restrict__ out) {
  __shared__ unsigned short u_s[256 * 64];   // 32KB circular row buffer (slot = row & 255)
  __shared__ float w_s[2][64][64];           // 32KB double-buffered tap chunk
  const int flat = blockIdx.x;               // 0..511
  const int dt = flat & 15;                  // flat&7 pins d-column to one XCD
  const int r  = (flat >> 4) & 7;
  const int pp = flat >> 7;                  // 0..3
  const int d0 = dt * 64;
  const int tid = threadIdx.x;
  const int dl = tid & 63;
  const int ig = tid >> 6;                   // wave 0..7

  const unsigned short* ubase = u + ((size_t)r * HALF_P + GUARD) * D_MODEL + d0;
  const int b_ = r >> 1, p = r & 1;

  // Stage 64 bf16 u rows [lo, lo+64): wave ig stages rows row0..row0+7, lane: 16B each.
#define STAGE64(lo)                                                                     \
  {                                                                                     \
    int row0 = (lo) + ig * 8;                                                           \
    const unsigned short* src = ubase + (size_t)(row0 + (dl >> 3)) * D_MODEL + (dl & 7) * 8; \
    __builtin_amdgcn_global_load_lds((const GAS void*)src,                              \
                                     (LAS void*)(u_s + (row0 & 255) * 64, 16, 0, 0);    \
  }

  // (note: macro above must compile -- parenthesization fixed below in real def)
#undef STAGE64
#define STAGE64(lo)                                                                     \
  {                                                                                     \
    int row0 = (lo) + ig * 8;                                                           \
    const unsigned short* src = ubase + (size_t)(row0 + (dl >> 3)) * D_MODEL + (dl & 7) * 8; \
    __builtin_amdgcn_global_load_lds((const GAS void*)src,                              \
                                     (LAS void*)(u_s + ((row0 & 255) * 64)), 16, 0, 0); \
  }

  // Stage 64 fp32 w rows [64*chunk, +64) into w_s[chunk&1]: 1024 x 16B by 512 threads x 2.
#define STAGEW(chunk)                                                                   \
  {                                                                                     \
    float* wdst = &w_s[(chunk) & 1][0][0];                                              \
    const float* wsrc = we + (size_t)(chunk) * 64 * D_MODEL + d0;                       \
    _Pragma("unroll") for (int q = 0; q < 2; ++q) {                                     \
      int f = tid + q * 512;                                                            \
      const float* s = wsrc + (size_t)(f >> 4) * D_MODEL + (f & 15) * 4;                \
      __builtin_amdgcn_global_load_lds((const GAS void*)s,                              \
                                       (LAS void*)(wdst + f * 4), 16, 0, 0);            \
    }                                                                                   \
  }

  // u LDS group read: rows urow-7..urow (base_row = (urow-7)&255, multiple of 8 -> no wrap)
#define LDSU(buf)                                                                       \
  {                                                                                     \
    int base_row = (urow - 7) & 255;                                                    \
    const unsigned short* ap = u_s + base_row * 64 + dl;                                \
    _Pragma("unroll") for (int t = 0; t < 8; ++t) {                                     \
      unsigned int hv = ap[(7 - t) * 64];                                               \
      buf[t] = __uint_as_float(hv << 16);                                               \
    }                                                                                   \
    urow -= 8;                                                                          \
  }

#define LDW(buf, g)                                                                     \
  {                                                                                     \
    _Pragma("unroll") for (int t = 0; t < 8; ++t)                                       \
      buf[t] = wptr[((g) * 8 + t) * 64];                                                \
  }

#pragma unroll 1
  for (int tt = 0; tt < 2; ++tt) {
    const int a = tt ? pp : (7 - pp);   // heavy tile first; 18 chunks total per block
    const int i0 = a * 128;
    const int ibase = i0 + ig * 16;
    const int niter = 2 * a + 2;        // 64-tap chunks

    STAGE64(i0 - 64); STAGE64(i0); STAGE64(i0 + 64);
    STAGEW(0);
    __syncthreads();

    float acc[16], win[16];
#pragma unroll
    for (int o = 0; o < 16; ++o) {
      acc[o] = 0.f;
      unsigned int hv = u_s[((ibase + o) & 255) * 64 + dl];
      win[o] = __uint_as_float(hv << 16);
    }

    float bu0[8], bu1[8], bw0[8], bw1[8];
    int urow = ibase - 1;

#pragma unroll 1
    for (int c = 0; c < niter; ++c) {
      STAGE64(i0 - 64 * c - 128);       // u rows for chunk c+1 (slots not live this chunk)
      STAGEW(c + 1);                    // w rows for chunk c+1 (opposite buffer)
      const float* wptr = &w_s[c & 1][0][dl];
      LDW(bw0, 0); LDSU(bu0);
      LDW(bw1, 1); LDSU(bu1); tap_group<0>(bu0, bw0, win, acc);
      LDW(bw0, 2); LDSU(bu0); tap_group<8>(bu1, bw1, win, acc);
      LDW(bw1, 3); LDSU(bu1); tap_group<0>(bu0, bw0, win, acc);
      LDW(bw0, 4); LDSU(bu0); tap_group<8>(bu1, bw1, win, acc);
      LDW(bw1, 5); LDSU(bu1); tap_group<0>(bu0, bw0, win, acc);
      LDW(bw0, 6); LDSU(bu0); tap_group<8>(bu1, bw1, win, acc);
      LDW(bw1, 7); LDSU(bu1); tap_group<0>(bu0, bw0, win, acc);
                              tap_group<8>(bu1, bw1, win, acc);
      __syncthreads();
    }

#pragma unroll
    for (int o = 0; o < 16; ++o)
      out[((size_t)b_ * SEQ + 2 * (ibase + o) + p) * D_MODEL + d0 + dl] = acc[o];
  }
#undef STAGE64
#undef STAGEW
#undef LDSU
#undef LDW
}

extern "C" void kernel_launch(void* const* d_in, const int* in_sizes, int n_in,
                              void* d_out, int out_size, void* d_ws, size_t ws_size,
                              hipStream_t stream) {
  const float* x   = (const float*)d_in[0];   // [4][2048][1024]
  const float* Mi  = (const float*)d_in[1];   // [1024][1024]
  const float* Mf  = (const float*)d_in[2];   // [24][1024]
  const float* phi = (const float*)d_in[3];   // [2048][24]
  float* out = (float*)d_out;

  // x_bf (16MB) and Mt (2MB) live in d_out -- dead before conv writes out.
  unsigned short* x_bf = (unsigned short*)d_out;
  unsigned short* Mt   = (unsigned short*)((char*)d_out + (16u << 20));

  char* ws = (char*)d_ws;
  float* we          = (float*)(ws);                         // 1120*4KB = 4.59 MB
  unsigned short* u  = (unsigned short*)(ws + (5u << 20));   // 8*1216*1024*2 = 19.9 MB

  hipLaunchKernelGGL(k_zero_guard, dim3(96, 8), dim3(256), 0, stream, (float4*)u);
  hipLaunchKernelGGL(k_convert_x, dim3(8192), dim3(256), 0, stream, x, x_bf, 2097152);
  hipLaunchKernelGGL(k_transpose_M, dim3(32, 32), dim3(256), 0, stream, Mi, Mt);
  hipLaunchKernelGGL(k_we, dim3(WE_ROWS), dim3(256), 0, stream, phi, Mf, we);
  hipLaunchKernelGGL(k_gemm, dim3(64, 8), dim3(256), 0, stream, x_bf, Mt, u);
  hipLaunchKernelGGL(k_conv, dim3(512), dim3(512), 0, stream, u, we, out);
}

// Round 8
// 143.801 us; speedup vs baseline: 1.9236x; 1.2893x over previous
//
#include <hip/hip_runtime.h>
#include <stdint.h>

#define D_MODEL 1024
#define SEQ 2048
#define HALF 1024
#define K_EIG 24
#define WE_PAIRS 544   // 512 real tap-pairs + 32 zero (staging overrun)
#define GUARD 192      // zero rows before EACH slice
#define HALF_P (HALF + GUARD)

typedef __attribute__((ext_vector_type(8))) short bf16x8;
typedef __attribute__((ext_vector_type(4))) float f32x4;
typedef _Float16 f16;
typedef _Float16 f16x2 __attribute__((ext_vector_type(2)));
typedef unsigned int uint;

#define GAS __attribute__((address_space(1)))
#define LAS __attribute__((address_space(3)))

static __device__ __forceinline__ unsigned short f2bf(float f) {
  union { float f; uint32_t u; } v; v.f = f;
  uint32_t u = v.u;
  u += 0x7FFFu + ((u >> 16) & 1u);
  return (unsigned short)(u >> 16);
}

static __device__ __forceinline__ float dot2(uint w2, uint u2, float c) {
  return __builtin_amdgcn_fdot2(__builtin_bit_cast(f16x2, w2),
                                __builtin_bit_cast(f16x2, u2), c, false);
}

// ---------------- x (fp32) -> bf16 ----------------
__global__ void k_convert_x(const float* __restrict__ x, unsigned short* __restrict__ xb, int n4) {
  int idx = blockIdx.x * blockDim.x + threadIdx.x;
  if (idx < n4) {
    float4 v = ((const float4*)x)[idx];
    ushort4 o;
    o.x = f2bf(v.x); o.y = f2bf(v.y); o.z = f2bf(v.z); o.w = f2bf(v.w);
    ((ushort4*)xb)[idx] = o;
  }
}

// ---------------- zero the per-slice guard rows of u (f16) ----------------
__global__ void k_zero_guard(float4* __restrict__ u) {
  int off = blockIdx.x * 256 + threadIdx.x;   // grid (96,8): 24576 float4 per slice
  int r = blockIdx.y;
  u[(size_t)r * (HALF_P * 128) + off] = make_float4(0.f, 0.f, 0.f, 0.f);
}

// ------------- M_inputs [K][N] fp32 -> Mt [N][K] bf16 -------------
__global__ void k_transpose_M(const float* __restrict__ M, unsigned short* __restrict__ Mt) {
  __shared__ float tile[32][33];
  int k0 = blockIdx.y * 32, n0 = blockIdx.x * 32;
  int tx = threadIdx.x & 31, ty = threadIdx.x >> 5;
  #pragma unroll
  for (int r = 0; r < 32; r += 8)
    tile[ty + r][tx] = M[(size_t)(k0 + ty + r) * D_MODEL + n0 + tx];
  __syncthreads();
  #pragma unroll
  for (int r = 0; r < 32; r += 8)
    Mt[(size_t)(n0 + ty + r) * D_MODEL + k0 + tx] = f2bf(tile[tx][ty + r]);
}

// ------------- we_pk[jp][d] = pack_f16( 2*sum_k phi[4jp,k]Mf[k,d], 2*sum_k phi[4jp+2,k]Mf[k,d] ) -------------
__global__ void k_we(const float* __restrict__ phi, const float* __restrict__ Mf,
                     uint* __restrict__ we_pk) {
  int jp = blockIdx.x;
  if (jp >= 512) {
    for (int d = threadIdx.x; d < D_MODEL; d += blockDim.x)
      we_pk[(size_t)jp * D_MODEL + d] = 0u;
    return;
  }
  __shared__ float ph[2][K_EIG];
  if (threadIdx.x < K_EIG) {
    ph[0][threadIdx.x] = phi[(size_t)(4 * jp) * K_EIG + threadIdx.x];
    ph[1][threadIdx.x] = phi[(size_t)(4 * jp + 2) * K_EIG + threadIdx.x];
  }
  __syncthreads();
  for (int d = threadIdx.x; d < D_MODEL; d += blockDim.x) {
    float s0 = 0.f, s1 = 0.f;
    #pragma unroll
    for (int k = 0; k < K_EIG; ++k) {
      float mv = Mf[(size_t)k * D_MODEL + d];
      s0 = fmaf(ph[0][k], mv, s0);
      s1 = fmaf(ph[1][k], mv, s1);
    }
    f16 h0 = (f16)(2.0f * s0), h1 = (f16)(2.0f * s1);
    we_pk[(size_t)jp * D_MODEL + d] =
        (uint)__builtin_bit_cast(unsigned short, h0) |
        ((uint)__builtin_bit_cast(unsigned short, h1) << 16);
  }
}

// ------------- u = x @ M (bf16 MFMA, B^T input), epilogue writes padded f16 u_h[r][GUARD+i][d] -------------
__global__ __launch_bounds__(256) void k_gemm(const unsigned short* __restrict__ A,
                                              const unsigned short* __restrict__ Bt,
                                              f16* __restrict__ U) {
  __shared__ unsigned short As[128 * 32];
  __shared__ unsigned short Bs[128 * 32];
  const int m0 = (int)blockIdx.x * 128;
  const int n0 = (int)blockIdx.y * 128;
  const int tid = threadIdx.x;
  const int lane = tid & 63;
  const int wave = tid >> 6;
  const int wm = wave >> 1, wn = wave & 1;
  const int srow = lane >> 2;
  const int skoff = (lane & 3) * 8;

  f32x4 acc[4][4] = {};

  for (int k0 = 0; k0 < 1024; k0 += 32) {
    __syncthreads();
    #pragma unroll
    for (int c = 0; c < 2; ++c) {
      int rbase = wave * 32 + c * 16;
      const unsigned short* src = A + (size_t)(m0 + rbase + srow) * 1024 + k0 + skoff;
      __builtin_amdgcn_global_load_lds((const GAS void*)src, (LAS void*)(As + rbase * 32), 16, 0, 0);
    }
    #pragma unroll
    for (int c = 0; c < 2; ++c) {
      int rbase = wave * 32 + c * 16;
      const unsigned short* src = Bt + (size_t)(n0 + rbase + srow) * 1024 + k0 + skoff;
      __builtin_amdgcn_global_load_lds((const GAS void*)src, (LAS void*)(Bs + rbase * 32), 16, 0, 0);
    }
    __syncthreads();

    bf16x8 a[4], b[4];
    #pragma unroll
    for (int mt = 0; mt < 4; ++mt)
      a[mt] = *(const bf16x8*)(As + ((wm * 64 + mt * 16 + (lane & 15)) * 32 + (lane >> 4) * 8));
    #pragma unroll
    for (int nt = 0; nt < 4; ++nt)
      b[nt] = *(const bf16x8*)(Bs + ((wn * 64 + nt * 16 + (lane & 15)) * 32 + (lane >> 4) * 8));
    #pragma unroll
    for (int mt = 0; mt < 4; ++mt)
      #pragma unroll
      for (int nt = 0; nt < 4; ++nt)
        acc[mt][nt] = __builtin_amdgcn_mfma_f32_16x16x32_bf16(a[mt], b[nt], acc[mt][nt], 0, 0, 0);
  }

  const int crow = (lane >> 4) * 4;
  const int ccol = lane & 15;
  #pragma unroll
  for (int mt = 0; mt < 4; ++mt) {
    #pragma unroll
    for (int q = 0; q < 4; ++q) {
      int m = m0 + wm * 64 + mt * 16 + crow + q;
      int b_ = m >> 11;
      int t = m & 2047;
      int r = (b_ << 1) | (t & 1);
      int i = t >> 1;
      f16* dst = U + ((size_t)r * HALF_P + GUARD + i) * D_MODEL;
      #pragma unroll
      for (int nt = 0; nt < 4; ++nt)
        dst[n0 + wn * 64 + nt * 16 + ccol] = (f16)acc[mt][nt][q];
    }
  }
}

// ------------- depthwise causal conv: f16 u ring (32KB) + packed f16 w (16KB) in LDS, dot2 taps -------------
// 512 thr = 64 d-lanes x 8 waves, 16 outputs/thread. i-tile 128, pairs (a,7-a): 18 chunks/block.
// Window pw[32]: packed f16 pair (lo=u[row], hi=u[row-1]); circular, off alternates {0,16} per 16-tap block.
__global__ __launch_bounds__(512, 4) void k_conv(const f16* __restrict__ u,
                                                 const uint* __restrict__ we_pk,
                                                 float* __restrict__ out) {
  __shared__ unsigned short u_s[256 * 64];   // 32KB ring (slot = row & 255)
  __shared__ uint w_sU[2 * 32 * 64];         // 16KB: 2 buffers x 32 tap-pairs x 64 d
  const int flat = blockIdx.x;               // 0..511
  const int dt = flat & 15;                  // flat&7 pins d-column to one XCD
  const int r  = (flat >> 4) & 7;
  const int pp = flat >> 7;                  // 0..3
  const int d0 = dt * 64;
  const int tid = threadIdx.x;
  const int dl = tid & 63;
  const int ig = tid >> 6;                   // wave 0..7

  const f16* ubase = u + ((size_t)r * HALF_P + GUARD) * D_MODEL + d0;
  const int b_ = r >> 1, p = r & 1;

  // stage 64 f16 rows [lo, lo+64): wave ig stages rows row0..row0+7, 16B/lane
#define STAGE64(lo)                                                                     \
  {                                                                                     \
    int row0 = (lo) + ig * 8;                                                           \
    const f16* src = ubase + (size_t)(row0 + (dl >> 3)) * D_MODEL + (dl & 7) * 8;       \
    __builtin_amdgcn_global_load_lds((const GAS void*)src,                              \
                                     (LAS void*)(u_s + ((row0 & 255) * 64)), 16, 0, 0); \
  }

  // stage 32 packed w rows of chunk `ch` into buffer ch&1 (8KB, 1 load/thread)
#define STAGEW(ch)                                                                      \
  {                                                                                     \
    const uint* s = we_pk + (size_t)((ch) * 32 + (tid >> 4)) * D_MODEL + d0 + (tid & 15) * 4; \
    __builtin_amdgcn_global_load_lds((const GAS void*)s,                                \
                                     (LAS void*)(w_sU + ((ch) & 1) * 2048 + tid * 4), 16, 0, 0); \
  }

#define LOADW(dst, pbase)                                                               \
  {                                                                                     \
    _Pragma("unroll") for (int i_ = 0; i_ < 8; ++i_)                                    \
      (dst)[i_] = wld[((pbase) + i_) * 64];                                             \
  }

  // build pw[(j+TOFF)&31] for j=0..15: rows [Sv, Sv+16] from ring; Sv % 16 == 0
#define BUILD16(TOFF, Sv)                                                               \
  {                                                                                     \
    int S_ = (Sv);                                                                      \
    int bo_ = ((S_ & 255) * 64) + dl;                                                   \
    int bo2_ = (((S_ + 16) & 255) * 64) + dl;                                           \
    ushort rr[17];                                                                      \
    _Pragma("unroll") for (int j = 0; j < 16; ++j) rr[j] = u_s[bo_ + j * 64];           \
    rr[16] = u_s[bo2_];                                                                 \
    _Pragma("unroll") for (int j = 1; j < 16; j += 2)                                   \
      pw[(j + (TOFF)) & 31] = (uint)rr[j + 1] | ((uint)rr[j] << 16);                    \
    pw[((TOFF)) & 31] = (uint)rr[1] | ((uint)rr[0] << 16);                              \
    _Pragma("unroll") for (int j = 2; j < 16; j += 2)                                   \
      pw[(j + (TOFF)) & 31] = __builtin_amdgcn_perm(pw[(j + 1 + (TOFF)) & 31],          \
                                                    pw[(j - 1 + (TOFF)) & 31], 0x01000706u); \
  }

  // 16-tap block: 8 tap-pairs, window offset OFF
#define DOT2BLK(OFF, BW)                                                                \
  {                                                                                     \
    _Pragma("unroll") for (int s = 0; s < 8; ++s) {                                     \
      uint wp_ = (BW)[s];                                                               \
      _Pragma("unroll") for (int o = 0; o < 16; ++o)                                    \
        acc[o] = dot2(wp_, pw[(o + 47 - 2 * s + (OFF)) & 31], acc[o]);                  \
    }                                                                                   \
  }

#pragma unroll 1
  for (int tt = 0; tt < 2; ++tt) {
    const int a = tt ? pp : (7 - pp);   // heavy tile first; 18 chunks total per block
    const int i0 = a * 128;
    const int ibase = i0 + ig * 16;
    const int niter = 2 * a + 2;        // 64-tap chunks

    STAGE64(i0 - 64); STAGE64(i0); STAGE64(i0 + 64);
    STAGEW(0);
    __syncthreads();

    float acc[16];
    uint pw[32];
    uint bwA[8], bwB[8];
#pragma unroll
    for (int o = 0; o < 16; ++o) acc[o] = 0.f;

    // initial window: pw[m] = (u[ibase-15+m], u[ibase-16+m]) for m=0..30; rows [ibase-16, ibase+15]
    {
      int S_ = ibase - 16;
      int bo_ = ((S_ & 255) * 64) + dl;
      int bo2_ = (((S_ + 16) & 255) * 64) + dl;
      ushort rr[32];
#pragma unroll
      for (int j = 0; j < 16; ++j) rr[j] = u_s[bo_ + j * 64];
#pragma unroll
      for (int j = 16; j < 32; ++j) rr[j] = u_s[bo2_ + (j - 16) * 64];
#pragma unroll
      for (int m = 1; m < 31; m += 2) pw[m] = (uint)rr[m + 1] | ((uint)rr[m] << 16);
      pw[0] = (uint)rr[1] | ((uint)rr[0] << 16);
      pw[30] = (uint)rr[31] | ((uint)rr[30] << 16);
#pragma unroll
      for (int m = 2; m < 30; m += 2)
        pw[m] = __builtin_amdgcn_perm(pw[m + 1], pw[m - 1], 0x01000706u);
      pw[31] = 0u;
    }

    {
      const uint* wld = w_sU + 0 * 2048 + dl;
      LOADW(bwA, 0);
    }

#pragma unroll 1
    for (int c = 0; c < niter; ++c) {
      STAGE64(i0 - 64 * c - 128);        // u rows for chunk c+1
      STAGEW(c + 1);                     // w pairs for chunk c+1 (other buffer)
      const uint* wld = w_sU + (c & 1) * 2048 + dl;
      if (c > 0) {                       // deferred: window + w for block0 of this chunk
        BUILD16(0, ibase - 64 * c - 16);
        LOADW(bwA, 0);
      }
      DOT2BLK(0, bwA);  BUILD16(16, ibase - 64 * c - 32); LOADW(bwB, 8);
      DOT2BLK(16, bwB); BUILD16(0,  ibase - 64 * c - 48); LOADW(bwA, 16);
      DOT2BLK(0, bwA);  BUILD16(16, ibase - 64 * c - 64); LOADW(bwB, 24);
      DOT2BLK(16, bwB);
      __syncthreads();
    }

#pragma unroll
    for (int o = 0; o < 16; ++o)
      out[((size_t)b_ * SEQ + 2 * (ibase + o) + p) * D_MODEL + d0 + dl] = acc[o];
  }
#undef STAGE64
#undef STAGEW
#undef LOADW
#undef BUILD16
#undef DOT2BLK
}

extern "C" void kernel_launch(void* const* d_in, const int* in_sizes, int n_in,
                              void* d_out, int out_size, void* d_ws, size_t ws_size,
                              hipStream_t stream) {
  const float* x   = (const float*)d_in[0];   // [4][2048][1024]
  const float* Mi  = (const float*)d_in[1];   // [1024][1024]
  const float* Mf  = (const float*)d_in[2];   // [24][1024]
  const float* phi = (const float*)d_in[3];   // [2048][24]
  float* out = (float*)d_out;

  // x_bf (16MB) and Mt (2MB) live in d_out -- dead before conv writes out.
  unsigned short* x_bf = (unsigned short*)d_out;
  unsigned short* Mt   = (unsigned short*)((char*)d_out + (16u << 20));

  char* ws = (char*)d_ws;
  uint* we_pk = (uint*)(ws);                       // 544*1024*4 = 2.2 MB
  f16* u      = (f16*)(ws + (3u << 20));           // 8*1216*1024*2 = 19.9 MB

  hipLaunchKernelGGL(k_zero_guard, dim3(96, 8), dim3(256), 0, stream, (float4*)u);
  hipLaunchKernelGGL(k_convert_x, dim3(8192), dim3(256), 0, stream, x, x_bf, 2097152);
  hipLaunchKernelGGL(k_transpose_M, dim3(32, 32), dim3(256), 0, stream, Mi, Mt);
  hipLaunchKernelGGL(k_we, dim3(WE_PAIRS), dim3(256), 0, stream, phi, Mf, we_pk);
  hipLaunchKernelGGL(k_gemm, dim3(64, 8), dim3(256), 0, stream, x_bf, Mt, u);
  hipLaunchKernelGGL(k_conv, dim3(512), dim3(512), 0, stream, u, we_pk, out);
}